// Round 5
// baseline (277.858 us; speedup 1.0000x reference)
//
#include <hip/hip_runtime.h>

#define BATCH 2
#define NPART 32768
#define GD 64
#define NVOX (BATCH * GD * GD * GD)   // 524288

typedef unsigned short ushortT;
typedef __attribute__((ext_vector_type(8))) short short8;
typedef __attribute__((ext_vector_type(16))) float float16;

__device__ __forceinline__ float poly6_c() {
    const double H9 = 1.0 / 35184372088832.0; // 0.03125^9 == 2^-45 (exact)
    return (float)(315.0 / (64.0 * 3.14159265358979323846 * H9));
}

__device__ __forceinline__ ushortT bf16_rne(float f) {
    unsigned int u = __float_as_uint(f);
    u = (u + 0x7fffu + ((u >> 16) & 1u)) >> 16;   // round-to-nearest-even
    return (ushortT)u;
}

__device__ __forceinline__ int imax(int a, int b) { return a > b ? a : b; }
__device__ __forceinline__ int imin(int a, int b) { return a < b ? a : b; }

// async global->LDS, 16 B per lane; LDS dest = wave-uniform base + lane*16
__device__ __forceinline__ void load_lds16(const void* g, void* l) {
    __builtin_amdgcn_global_load_lds(
        (const __attribute__((address_space(1))) void*)g,
        (__attribute__((address_space(3))) void*)l, 16, 0, 0);
}

// ---------------- fused prep: zero ints (blocks 0..512) + weight repack ----
// ICG=4 layers use half-major kt order: kt = half*27 + (dx*3+dz)*3 + dy,
// with K=16 spanning ic = half*16 + q*8 + j.  Matches the conv kernel's
// phase structure (one K-half per phase).
__global__ __launch_bounds__(256) void prep_kernel(
    int* __restrict__ zp,
    const float* __restrict__ W0, const float* __restrict__ W1,
    const float* __restrict__ W2, const float* __restrict__ W3,
    short* __restrict__ Bp) {
    int bid = blockIdx.x, tid = threadIdx.x;
    if (bid < 513) {
        int t = bid * 256 + tid;
        if (t < 131088) zp[t] = 0;
        return;
    }
    int t = (bid - 513) * 256 + tid;
    if (t >= 176 * 512) return;
    int kt = t >> 9;
    int l = (t >> 3) & 63, j = t & 7;
    int n = l & 31, q = l >> 5;
    float v = 0.f;
    if (kt < 14) {
        // W0: O=32, I=4, packed as 8-ch K with 2 taps per kt
        int k = kt * 16 + 8 * q + j;
        int tap = k >> 3, ic = k & 7;
        if (tap < 27 && ic < 4) v = W0[(n * 4 + ic) * 27 + tap];
    } else {
        const float* W; int O, s;
        if (kt < 68)       { W = W1; O = 32; s = kt - 14; }
        else if (kt < 122) { W = W2; O = 32; s = kt - 68; }
        else               { W = W3; O = 4;  s = kt - 122; }
        int h = s / 27, ss = s - h * 27;
        int gI = ss / 3, dy = ss - gI * 3;
        int dx = gI / 3, dz = gI - dx * 3;
        int tap = dx * 9 + dy * 3 + dz;
        int ic = h * 16 + q * 8 + j;
        if (n < O) v = W[(n * 32 + ic) * 27 + tap];
    }
    Bp[t] = (short)bf16_rne(v);
}

// ---------------- bin count: particle -> 2^3-cell bin histogram ----------------
__global__ __launch_bounds__(256) void bin_count_kernel(
    const float* __restrict__ locs, int* __restrict__ counts) {
    int t = blockIdx.x * blockDim.x + threadIdx.x;
    if (t >= BATCH * NPART) return;
    int b = t >> 15;
    int bx = ((int)floorf(locs[t * 3 + 0] * 64.0f)) >> 1;
    int by = ((int)floorf(locs[t * 3 + 1] * 64.0f)) >> 1;
    int bz = ((int)floorf(locs[t * 3 + 2] * 64.0f)) >> 1;
    atomicAdd(&counts[b * 32768 + ((bx * 32) + by) * 32 + bz], 1);
}

// ---------------- scan, level A: per-256-block exclusive scan ----------------
__global__ __launch_bounds__(256) void scanA_kernel(
    const int* __restrict__ counts, int* __restrict__ offsets,
    int* __restrict__ blockSum) {
    __shared__ int sh[256];
    int tid = threadIdx.x, g = blockIdx.x;        // 256 blocks x 256
    int v = counts[g * 256 + tid];
    sh[tid] = v;
    __syncthreads();
    for (int off = 1; off < 256; off <<= 1) {
        int u = (tid >= off) ? sh[tid - off] : 0;
        __syncthreads();
        sh[tid] += u;
        __syncthreads();
    }
    offsets[g * 256 + tid] = sh[tid] - v;         // exclusive
    if (tid == 255) blockSum[g] = sh[255];
}

// ---------------- scan, level B: add block prefixes ----------------
__global__ __launch_bounds__(256) void scanB_kernel(
    int* __restrict__ offsets, const int* __restrict__ blockSum) {
    __shared__ int sh[256];
    int tid = threadIdx.x, g = blockIdx.x;
    sh[tid] = (tid < g) ? blockSum[tid] : 0;
    __syncthreads();
    for (int off = 128; off > 0; off >>= 1) {
        if (tid < off) sh[tid] += sh[tid + off];
        __syncthreads();
    }
    offsets[g * 256 + tid] += sh[0];
    if (g == 255 && tid == 255) offsets[65536] = BATCH * NPART;  // sentinel
}

// ---------------- scatter particles into binned payload ----------------
__global__ __launch_bounds__(256) void bin_scatter_kernel(
    const float* __restrict__ locs, const float* __restrict__ data,
    const float* __restrict__ density, const int* __restrict__ offsets,
    int* __restrict__ cursor, float* __restrict__ payload) {
    int t = blockIdx.x * blockDim.x + threadIdx.x;
    if (t >= BATCH * NPART) return;
    int b = t >> 15;
    float px = locs[t * 3 + 0];
    float py = locs[t * 3 + 1];
    float pz = locs[t * 3 + 2];
    int bx = ((int)floorf(px * 64.0f)) >> 1;
    int by = ((int)floorf(py * 64.0f)) >> 1;
    int bz = ((int)floorf(pz * 64.0f)) >> 1;
    int bb = b * 32768 + ((bx * 32) + by) * 32 + bz;
    int slot = atomicAdd(&cursor[bb], 1);
    int idx = offsets[bb] + slot;
    float inv_d = 1.0f / density[t];
    float4 p0 = {px, py, pz, data[t * 4 + 0] * inv_d};
    float4 p1 = {data[t * 4 + 1] * inv_d, data[t * 4 + 2] * inv_d,
                 data[t * 4 + 3] * inv_d, 0.f};
    *(float4*)(payload + idx * 8)     = p0;
    *(float4*)(payload + idx * 8 + 4) = p1;
}

// ---------------- cell-owner gather splat: no atomics ----------------
__global__ __launch_bounds__(256) void splat_gather_kernel(
    const float* __restrict__ payload, const int* __restrict__ offsets,
    ushortT* __restrict__ g8) {
    __shared__ float plist[256 * 8];
    __shared__ int segS[36];
    __shared__ int segP[37];
    __shared__ int shTot[1];

    int wg = blockIdx.x;                          // 1024 = b*512 + sb
    int sb = wg & 511, b = wg >> 9;
    int X0 = (sb >> 6) * 8, Y0 = ((sb >> 3) & 7) * 8, Z0 = (sb & 7) * 8;
    int tid = threadIdx.x;

    int bxlo = imax(0, (X0 - 2) >> 1), bxhi = imin(31, (X0 + 9) >> 1);
    int bylo = imax(0, (Y0 - 2) >> 1), byhi = imin(31, (Y0 + 9) >> 1);
    int bzlo = imax(0, (Z0 - 2) >> 1), bzhi = imin(31, (Z0 + 9) >> 1);
    int ny = byhi - bylo + 1;
    int ns = (bxhi - bxlo + 1) * ny;
    if (tid < ns) {
        int bx = bxlo + tid / ny, by = bylo + tid % ny;
        int row = b * 32768 + (bx * 32 + by) * 32;
        int s = offsets[row + bzlo];
        int e = offsets[row + bzhi + 1];
        segS[tid] = s;
        segP[tid] = e - s;
    }
    __syncthreads();
    if (tid == 0) {
        int p = 0;
        for (int k = 0; k < ns; ++k) { int len = segP[k]; segP[k] = p; p += len; }
        segP[ns] = p;
        shTot[0] = p;
    }
    __syncthreads();

    const float step = 0.015625f;
    const float h2 = 0.03125f * 0.03125f;
    const float cc = poly6_c();
    int total = shTot[0];

    int l = tid & 63, w = tid >> 6;
    int cx = X0 + 4 * (w >> 1) + (l >> 4);
    int cy = Y0 + 4 * (w & 1) + ((l >> 2) & 3);
    int cz0 = Z0 + (l & 3);
    float xc  = ((float)cx  + 0.5f) * step;
    float yc  = ((float)cy  + 0.5f) * step;
    float zc0 = ((float)cz0 + 0.5f) * step;
    float zc1 = zc0 + 4.0f * step;

    float a00 = 0.f, a01 = 0.f, a02 = 0.f, a03 = 0.f;
    float a10 = 0.f, a11 = 0.f, a12 = 0.f, a13 = 0.f;

    int nchunks = (total + 255) >> 8;
    for (int ch = 0; ch < nchunks; ++ch) {
        __syncthreads();
        int jj = (ch << 8) + tid;
        if (jj < total) {
            int k = 0;
            while (jj >= segP[k + 1]) ++k;
            int idx = segS[k] + (jj - segP[k]);
            *(float4*)(plist + tid * 8)     = *(const float4*)(payload + idx * 8);
            *(float4*)(plist + tid * 8 + 4) = *(const float4*)(payload + idx * 8 + 4);
        }
        __syncthreads();
        int cnt = imin(256, total - (ch << 8));
        for (int p = 0; p < cnt; ++p) {
            float4 pa = *(const float4*)(plist + p * 8);     // broadcast read
            float dx = pa.x - xc, dy = pa.y - yc;
            float dxy2 = fmaf(dy, dy, dx * dx);
            if (!__any(dxy2 <= h2)) continue;                // wave-coherent skip
            float4 pv = *(const float4*)(plist + p * 8 + 4);
            float dz0 = pa.z - zc0;
            float d20 = fmaf(dz0, dz0, dxy2);
            float u0 = fmaxf(h2 - d20, 0.f);
            float w0 = (cc * u0) * (u0 * u0);
            a00 = fmaf(w0, pa.w, a00);
            a01 = fmaf(w0, pv.x, a01);
            a02 = fmaf(w0, pv.y, a02);
            a03 = fmaf(w0, pv.z, a03);
            float dz1 = pa.z - zc1;
            float d21 = fmaf(dz1, dz1, dxy2);
            float u1 = fmaxf(h2 - d21, 0.f);
            float w1 = (cc * u1) * (u1 * u1);
            a10 = fmaf(w1, pa.w, a10);
            a11 = fmaf(w1, pv.x, a11);
            a12 = fmaf(w1, pv.y, a12);
            a13 = fmaf(w1, pv.z, a13);
        }
    }

    size_t cellBase = (size_t)(((b * 64 + cx) * 64 + cy) * 64);
    short8 o;
    o[0] = (short)bf16_rne(a00); o[1] = (short)bf16_rne(a01);
    o[2] = (short)bf16_rne(a02); o[3] = (short)bf16_rne(a03);
    o[4] = 0; o[5] = 0; o[6] = 0; o[7] = 0;
    *(short8*)(g8 + (cellBase + cz0) * 8) = o;
    o[0] = (short)bf16_rne(a10); o[1] = (short)bf16_rne(a11);
    o[2] = (short)bf16_rne(a12); o[3] = (short)bf16_rne(a13);
    *(short8*)(g8 + (cellBase + cz0 + 4) * 8) = o;
}

// ---------------- MFMA implicit-GEMM 3x3x3 conv (persistent, dbuf, 3/CU) ----
// 2x4-column tile x 32-z: wave owns one x-col (wx=w>>1) and a y-pair
// (wy2=(w&1)*2) with 2 accumulators.  Per-phase buffer = 4x6 cols x 2 icg
// x 34 z x 16 B = 26.1 KB; double-buffered = 52.2 KB -> 3 blocks/CU
// (3 waves/SIMD: enough TLP to overlap one wave's ds_read/VALU with
// another's MFMA -- R1 evidence: 3/CU beat 2/CU despite more traffic).
// Persistent: each block does 2 z-tiles x PH halves = pipelined phases;
// at each phase top: barrier (drains prev stage), issue next stage,
// compute current buffer.  icg halves temporally adjacent (no refetch).
template <int ICG, int KT, bool FINAL>
__global__ __launch_bounds__(256, 3) void mfma_conv_kernel(
    const ushortT* __restrict__ in, const short* __restrict__ Bpack,
    const float* __restrict__ bias, const float* __restrict__ alpha,
    const float* __restrict__ zguard, void* __restrict__ outv) {
    constexpr int CIN  = ICG * 8;
    constexpr int PH   = (ICG == 1) ? 1 : 2;              // phases per tile
    constexpr int NCHP = (ICG == 1) ? (24 * 34) : (24 * 2 * 34);  // 16B chunks
    constexpr int BUFS = NCHP * 8;                        // shorts per buffer
    __shared__ short lds[2 * BUFS];

    // XCD swizzle: contiguous slab per XCD (1024 blocks -> 128 per XCD)
    int wg = ((blockIdx.x & 7) << 7) | (blockIdx.x >> 3);
    int yq = wg & 15, xp = (wg >> 4) & 31, b = wg >> 9;
    int X0 = xp * 2, Y0 = yq * 4;
    int tid = threadIdx.x;
    const ushortT* inb = in + (size_t)b * (64 * 64 * 64 * CIN);

    int l = tid & 63, w = tid >> 6;
    int wx = w >> 1, wy2 = (w & 1) * 2;            // owned x-col, y-pair base
    int n = l & 31, q = l >> 5;
    int laneZ = (l & 31) * 8;                      // z-row offset (shorts)
    const short* bp = Bpack + (size_t)l * 8;
    float bval = FINAL ? (n < 4 ? bias[n] : 0.f) : bias[n];

    // issue one phase's staging (no wait) into buffer ph&1
    auto stage = [&](int ph) {
        int t = ph / PH, h = ph - t * PH;
        int zb = t * 32;
        short* dst = lds + (ph & 1) * BUFS;
#pragma unroll
        for (int it = 0; it < (NCHP + 255) / 256; ++it) {
            int ccid = it * 256 + tid;
            if (ccid < NCHP) {
                int col, icg2, zi;
                if constexpr (ICG == 1) {
                    col = ccid / 34; zi = ccid - col * 34; icg2 = 0;
                } else {
                    col = ccid / 68;
                    int rem = ccid - col * 68;
                    icg2 = rem / 34; zi = rem - icg2 * 34;
                }
                int gx = X0 + col / 6 - 1;
                int gy = Y0 + col % 6 - 1;
                int gz = zb + zi - 1;
                const void* src = (const void*)zguard;
                if ((unsigned)gx < 64u && (unsigned)gy < 64u && (unsigned)gz < 64u)
                    src = (const void*)(inb +
                        ((size_t)(((gx * 64) + gy) * 64 + gz)) * CIN + (h * 2 + icg2) * 8);
                load_lds16(src, (void*)(dst + ccid * 8));
            }
        }
    };

    stage(0);

#pragma unroll
    for (int tile = 0; tile < 2; ++tile) {
        int Z0 = tile * 32;
        float16 acc0, acc1;
#pragma unroll
        for (int r = 0; r < 16; ++r) { acc0[r] = bval; acc1[r] = bval; }

#pragma unroll
        for (int h = 0; h < PH; ++h) {
            int ph = tile * PH + h;
            __syncthreads();                       // stage(ph) arrived; buf free
            if (ph + 1 < 2 * PH) stage(ph + 1);    // issue-early, consume-late
            const short* lb = lds + (ph & 1) * BUFS;

            if constexpr (ICG == 1) {
                short8 bf[4];
#pragma unroll
                for (int i = 0; i < 4; ++i) bf[i] = *(const short8*)(bp + i * 512);
#pragma unroll
                for (int kt = 0; kt < KT; ++kt) {
                    short8 bcur = bf[kt & 3];
                    if (kt + 4 < KT) bf[kt & 3] = *(const short8*)(bp + (kt + 4) * 512);
                    int tap0 = kt * 2, tap1 = kt * 2 + 1;
                    if (tap1 > 26) tap1 = 26;      // B is zero there
                    int dx0 = tap0 / 9, r0 = tap0 - dx0 * 9, dy0 = r0 / 3, dz0 = r0 - dy0 * 3;
                    int dx1 = tap1 / 9, r1 = tap1 - dx1 * 9, dy1 = r1 / 3, dz1 = r1 - dy1 * 3;
#define AOFS1(c) (q ? ((((wx + dx1) * 6 + ((c) + dy1)) * 34 + dz1) * 8) \
                    : ((((wx + dx0) * 6 + ((c) + dy0)) * 34 + dz0) * 8))
                    short8 a0 = *(const short8*)(lb + AOFS1(wy2) + laneZ);
                    short8 a1 = *(const short8*)(lb + AOFS1(wy2 + 1) + laneZ);
#undef AOFS1
                    __builtin_amdgcn_s_setprio(1);
                    acc0 = __builtin_amdgcn_mfma_f32_32x32x16_bf16(a0, bcur, acc0, 0, 0, 0);
                    acc1 = __builtin_amdgcn_mfma_f32_32x32x16_bf16(a1, bcur, acc1, 0, 0, 0);
                    __builtin_amdgcn_s_setprio(0);
                }
            } else {
                short8 bf[4];
#pragma unroll
                for (int i = 0; i < 4; ++i)
                    bf[i] = *(const short8*)(bp + (h * 27 + i) * 512);
#pragma unroll
                for (int g = 0; g < 9; ++g) {
                    int dx = g / 3, dz = g - dx * 3;
                    short8 fr[4];
#pragma unroll
                    for (int k = 0; k < 4; ++k) {
                        int ofs = ((((wx + dx) * 6 + (wy2 + k)) * 2 + q) * 34 + dz) * 8;
                        fr[k] = *(const short8*)(lb + ofs + laneZ);
                    }
#pragma unroll
                    for (int dy = 0; dy < 3; ++dy) {
                        int k27 = g * 3 + dy;
                        short8 bcur = bf[k27 & 3];
                        if (k27 + 4 < 27)
                            bf[k27 & 3] = *(const short8*)(bp + (h * 27 + k27 + 4) * 512);
                        __builtin_amdgcn_s_setprio(1);
                        acc0 = __builtin_amdgcn_mfma_f32_32x32x16_bf16(fr[0 + dy], bcur, acc0, 0, 0, 0);
                        acc1 = __builtin_amdgcn_mfma_f32_32x32x16_bf16(fr[1 + dy], bcur, acc1, 0, 0, 0);
                        __builtin_amdgcn_s_setprio(0);
                    }
                }
            }
        }

        // epilogue overlaps the next tile's staging (already issued)
        size_t base0 = (size_t)(((b * 64 + X0 + wx) * 64 + (Y0 + wy2)) * 64) + Z0;
        if constexpr (FINAL) {
            float* out = (float*)outv;
            if (n < 4) {
#pragma unroll
                for (int r = 0; r < 16; ++r) {
                    int z = (r & 3) + 8 * (r >> 2) + 4 * q;
                    out[(base0 + z) * 4 + n]      = acc0[r];
                    out[(base0 + 64 + z) * 4 + n] = acc1[r];
                }
            }
        } else {
            float a = alpha[0];
            ushortT* out = (ushortT*)outv;
#pragma unroll
            for (int r = 0; r < 16; ++r) {
                int z = (r & 3) + 8 * (r >> 2) + 4 * q;
                float v0 = acc0[r]; v0 = v0 >= 0.f ? v0 : a * v0;
                out[(base0 + z) * 32 + n] = bf16_rne(v0);
                float v1 = acc1[r]; v1 = v1 >= 0.f ? v1 : a * v1;
                out[(base0 + 64 + z) * 32 + n] = bf16_rne(v1);
            }
        }
    }
}

// ---------------- grid2particles (trilinear gather, fp32 grid) ----------------
__global__ __launch_bounds__(256) void gather_kernel(
    const float* __restrict__ grid, const float* __restrict__ locs,
    float* __restrict__ out) {
    int t = blockIdx.x * blockDim.x + threadIdx.x;
    if (t >= BATCH * NPART) return;
    int b = t >> 15;

    float px = locs[t * 3 + 0] * 64.0f - 0.5f;
    float py = locs[t * 3 + 1] * 64.0f - 0.5f;
    float pz = locs[t * 3 + 2] * 64.0f - 0.5f;
    int ix = (int)floorf(px);
    int iy = (int)floorf(py);
    int iz = (int)floorf(pz);
    float fx = px - (float)ix;
    float fy = py - (float)iy;
    float fz = pz - (float)iz;

    const float* gb = grid + (size_t)b * GD * GD * GD * 4;
    float o0 = 0.f, o1 = 0.f, o2 = 0.f, o3 = 0.f;

#pragma unroll
    for (int dx = 0; dx < 2; ++dx) {
        int x = ix + dx;
        if ((unsigned)x > 63u) continue;
        float wx = dx ? fx : 1.0f - fx;
#pragma unroll
        for (int dy = 0; dy < 2; ++dy) {
            int y = iy + dy;
            if ((unsigned)y > 63u) continue;
            float wy = dy ? fy : 1.0f - fy;
#pragma unroll
            for (int dz = 0; dz < 2; ++dz) {
                int z = iz + dz;
                if ((unsigned)z > 63u) continue;
                float wz = dz ? fz : 1.0f - fz;
                float w = wx * wy * wz;
                const float4 g = *(const float4*)(gb + (size_t)(((x * GD) + y) * GD + z) * 4);
                o0 += w * g.x; o1 += w * g.y; o2 += w * g.z; o3 += w * g.w;
            }
        }
    }
    out[t * 4 + 0] = o0;
    out[t * 4 + 1] = o1;
    out[t * 4 + 2] = o2;
    out[t * 4 + 3] = o3;
}

extern "C" void kernel_launch(void* const* d_in, const int* in_sizes, int n_in,
                              void* d_out, int out_size, void* d_ws, size_t ws_size,
                              hipStream_t stream) {
    const float* locs    = (const float*)d_in[0];
    const float* data    = (const float*)d_in[1];
    const float* density = (const float*)d_in[2];
    const float* W0 = (const float*)d_in[3];
    const float* b0 = (const float*)d_in[4];
    const float* W1 = (const float*)d_in[5];
    const float* b1 = (const float*)d_in[6];
    const float* W2 = (const float*)d_in[7];
    const float* b2 = (const float*)d_in[8];
    const float* W3 = (const float*)d_in[9];
    const float* b3 = (const float*)d_in[10];
    const float* a0 = (const float*)d_in[11];
    const float* a1 = (const float*)d_in[12];
    const float* a2 = (const float*)d_in[13];
    float* out = (float*)d_out;

    char* ws = (char*)d_ws;
    ushortT* g8  = (ushortT*)(ws);                       // 8 MB bf16 8ch
    ushortT* gA  = (ushortT*)(ws + 8388608);             // 33.5 MB bf16 32ch
    ushortT* gB  = (ushortT*)(ws + 41943040);            // 33.5 MB bf16 32ch
    float*  gF   = (float*)(ws + 75497472);              // 8 MB fp32 4ch
    short*  Bp   = (short*)(ws + 83886080);              // 176*512*2 = 180224 B
    short*  Bp0  = Bp;                                   // kt 0..13
    short*  Bp1  = Bp + 14 * 512;                        // kt 14..67
    short*  Bp2  = Bp + 68 * 512;                        // kt 68..121
    short*  Bp3  = Bp + 122 * 512;                       // kt 122..175
    float* zguard   = (float*)(ws + 84066240);           // 64 B zeros (16 ints)
    int*   counts   = (int*)(ws + 84066304);             // 65536 ints
    int*   cursor   = (int*)(ws + 84328448);             // 65536 ints
    int*   offsets  = (int*)(ws + 84590592);             // 65537 ints
    int*   blockSum = (int*)(ws + 84852752);             // 256 ints
    float* payload  = (float*)(ws + 84853888);           // 65536*8 floats = 2 MB

    // ---- fused prep: zero (zguard+counts+cursor) + weight repack ----
    prep_kernel<<<513 + 352, 256, 0, stream>>>((int*)zguard, W0, W1, W2, W3, Bp);

    bin_count_kernel<<<(BATCH * NPART) / 256, 256, 0, stream>>>(locs, counts);
    scanA_kernel<<<256, 256, 0, stream>>>(counts, offsets, blockSum);
    scanB_kernel<<<256, 256, 0, stream>>>(offsets, blockSum);
    bin_scatter_kernel<<<(BATCH * NPART) / 256, 256, 0, stream>>>(
        locs, data, density, offsets, cursor, payload);

    // ---- particles -> bf16 grid (cell-owner gather, no atomics) ----
    splat_gather_kernel<<<BATCH * 512, 256, 0, stream>>>(payload, offsets, g8);

    // ---- conv chain (persistent dbuf, 2x4 tile, 3 blocks/CU) ----
    const int CGRID = 1024;   // 2 b x 32 xp x 16 yq (each block does zh 0,1)
    mfma_conv_kernel< 1, 14, false><<<CGRID, 256, 0, stream>>>(g8, Bp0, b0, a0, zguard, gA);
    mfma_conv_kernel< 4, 54, false><<<CGRID, 256, 0, stream>>>(gA, Bp1, b1, a1, zguard, gB);
    mfma_conv_kernel< 4, 54, false><<<CGRID, 256, 0, stream>>>(gB, Bp2, b2, a2, zguard, gA);
    mfma_conv_kernel< 4, 54, true ><<<CGRID, 256, 0, stream>>>(gA, Bp3, b3, b3, zguard, gF);

    // ---- grid -> particles ----
    gather_kernel<<<(BATCH * NPART) / 256, 256, 0, stream>>>(gF, locs, out);
}

// Round 6
// 239.763 us; speedup vs baseline: 1.1589x; 1.1589x over previous
//
#include <hip/hip_runtime.h>

#define BATCH 2
#define NPART 32768
#define GD 64
#define NVOX (BATCH * GD * GD * GD)   // 524288

typedef unsigned short ushortT;
typedef __attribute__((ext_vector_type(8))) short short8;
typedef __attribute__((ext_vector_type(16))) float float16;

__device__ __forceinline__ float poly6_c() {
    const double H9 = 1.0 / 35184372088832.0; // 0.03125^9 == 2^-45 (exact)
    return (float)(315.0 / (64.0 * 3.14159265358979323846 * H9));
}

__device__ __forceinline__ ushortT bf16_rne(float f) {
    unsigned int u = __float_as_uint(f);
    u = (u + 0x7fffu + ((u >> 16) & 1u)) >> 16;   // round-to-nearest-even
    return (ushortT)u;
}

__device__ __forceinline__ int imax(int a, int b) { return a > b ? a : b; }
__device__ __forceinline__ int imin(int a, int b) { return a < b ? a : b; }

// async global->LDS, 16 B per lane; LDS dest = wave-uniform base + lane*16
__device__ __forceinline__ void load_lds16(const void* g, void* l) {
    __builtin_amdgcn_global_load_lds(
        (const __attribute__((address_space(1))) void*)g,
        (__attribute__((address_space(3))) void*)l, 16, 0, 0);
}

// ---------------- fused prep: zero ints (blocks 0..512) + weight repack ----
// ICG=4 layers use half-major kt order: kt = half*27 + (dx*3+dz)*3 + dy,
// with K=16 spanning ic = half*16 + q*8 + j.  Matches the conv kernel's
// h-major phase order (one resident B-half in LDS at a time).
__global__ __launch_bounds__(256) void prep_kernel(
    int* __restrict__ zp,
    const float* __restrict__ W0, const float* __restrict__ W1,
    const float* __restrict__ W2, const float* __restrict__ W3,
    short* __restrict__ Bp) {
    int bid = blockIdx.x, tid = threadIdx.x;
    if (bid < 513) {
        int t = bid * 256 + tid;
        if (t < 131088) zp[t] = 0;
        return;
    }
    int t = (bid - 513) * 256 + tid;
    if (t >= 176 * 512) return;
    int kt = t >> 9;
    int l = (t >> 3) & 63, j = t & 7;
    int n = l & 31, q = l >> 5;
    float v = 0.f;
    if (kt < 14) {
        // W0: O=32, I=4, packed as 8-ch K with 2 taps per kt
        int k = kt * 16 + 8 * q + j;
        int tap = k >> 3, ic = k & 7;
        if (tap < 27 && ic < 4) v = W0[(n * 4 + ic) * 27 + tap];
    } else {
        const float* W; int O, s;
        if (kt < 68)       { W = W1; O = 32; s = kt - 14; }
        else if (kt < 122) { W = W2; O = 32; s = kt - 68; }
        else               { W = W3; O = 4;  s = kt - 122; }
        int h = s / 27, ss = s - h * 27;
        int gI = ss / 3, dy = ss - gI * 3;
        int dx = gI / 3, dz = gI - dx * 3;
        int tap = dx * 9 + dy * 3 + dz;
        int ic = h * 16 + q * 8 + j;
        if (n < O) v = W[(n * 32 + ic) * 27 + tap];
    }
    Bp[t] = (short)bf16_rne(v);
}

// ---------------- bin count: particle -> 2^3-cell bin histogram ----------------
__global__ __launch_bounds__(256) void bin_count_kernel(
    const float* __restrict__ locs, int* __restrict__ counts) {
    int t = blockIdx.x * blockDim.x + threadIdx.x;
    if (t >= BATCH * NPART) return;
    int b = t >> 15;
    int bx = ((int)floorf(locs[t * 3 + 0] * 64.0f)) >> 1;
    int by = ((int)floorf(locs[t * 3 + 1] * 64.0f)) >> 1;
    int bz = ((int)floorf(locs[t * 3 + 2] * 64.0f)) >> 1;
    atomicAdd(&counts[b * 32768 + ((bx * 32) + by) * 32 + bz], 1);
}

// ---------------- scan, level A: per-256-block exclusive scan ----------------
__global__ __launch_bounds__(256) void scanA_kernel(
    const int* __restrict__ counts, int* __restrict__ offsets,
    int* __restrict__ blockSum) {
    __shared__ int sh[256];
    int tid = threadIdx.x, g = blockIdx.x;        // 256 blocks x 256
    int v = counts[g * 256 + tid];
    sh[tid] = v;
    __syncthreads();
    for (int off = 1; off < 256; off <<= 1) {
        int u = (tid >= off) ? sh[tid - off] : 0;
        __syncthreads();
        sh[tid] += u;
        __syncthreads();
    }
    offsets[g * 256 + tid] = sh[tid] - v;         // exclusive
    if (tid == 255) blockSum[g] = sh[255];
}

// ---------------- scan, level B: add block prefixes ----------------
__global__ __launch_bounds__(256) void scanB_kernel(
    int* __restrict__ offsets, const int* __restrict__ blockSum) {
    __shared__ int sh[256];
    int tid = threadIdx.x, g = blockIdx.x;
    sh[tid] = (tid < g) ? blockSum[tid] : 0;
    __syncthreads();
    for (int off = 128; off > 0; off >>= 1) {
        if (tid < off) sh[tid] += sh[tid + off];
        __syncthreads();
    }
    offsets[g * 256 + tid] += sh[0];
    if (g == 255 && tid == 255) offsets[65536] = BATCH * NPART;  // sentinel
}

// ---------------- scatter particles into binned payload ----------------
__global__ __launch_bounds__(256) void bin_scatter_kernel(
    const float* __restrict__ locs, const float* __restrict__ data,
    const float* __restrict__ density, const int* __restrict__ offsets,
    int* __restrict__ cursor, float* __restrict__ payload) {
    int t = blockIdx.x * blockDim.x + threadIdx.x;
    if (t >= BATCH * NPART) return;
    int b = t >> 15;
    float px = locs[t * 3 + 0];
    float py = locs[t * 3 + 1];
    float pz = locs[t * 3 + 2];
    int bx = ((int)floorf(px * 64.0f)) >> 1;
    int by = ((int)floorf(py * 64.0f)) >> 1;
    int bz = ((int)floorf(pz * 64.0f)) >> 1;
    int bb = b * 32768 + ((bx * 32) + by) * 32 + bz;
    int slot = atomicAdd(&cursor[bb], 1);
    int idx = offsets[bb] + slot;
    float inv_d = 1.0f / density[t];
    float4 p0 = {px, py, pz, data[t * 4 + 0] * inv_d};
    float4 p1 = {data[t * 4 + 1] * inv_d, data[t * 4 + 2] * inv_d,
                 data[t * 4 + 3] * inv_d, 0.f};
    *(float4*)(payload + idx * 8)     = p0;
    *(float4*)(payload + idx * 8 + 4) = p1;
}

// ---------------- cell-owner gather splat: no atomics ----------------
__global__ __launch_bounds__(256) void splat_gather_kernel(
    const float* __restrict__ payload, const int* __restrict__ offsets,
    ushortT* __restrict__ g8) {
    __shared__ float plist[256 * 8];
    __shared__ int segS[36];
    __shared__ int segP[37];
    __shared__ int shTot[1];

    int wg = blockIdx.x;                          // 1024 = b*512 + sb
    int sb = wg & 511, b = wg >> 9;
    int X0 = (sb >> 6) * 8, Y0 = ((sb >> 3) & 7) * 8, Z0 = (sb & 7) * 8;
    int tid = threadIdx.x;

    int bxlo = imax(0, (X0 - 2) >> 1), bxhi = imin(31, (X0 + 9) >> 1);
    int bylo = imax(0, (Y0 - 2) >> 1), byhi = imin(31, (Y0 + 9) >> 1);
    int bzlo = imax(0, (Z0 - 2) >> 1), bzhi = imin(31, (Z0 + 9) >> 1);
    int ny = byhi - bylo + 1;
    int ns = (bxhi - bxlo + 1) * ny;
    if (tid < ns) {
        int bx = bxlo + tid / ny, by = bylo + tid % ny;
        int row = b * 32768 + (bx * 32 + by) * 32;
        int s = offsets[row + bzlo];
        int e = offsets[row + bzhi + 1];
        segS[tid] = s;
        segP[tid] = e - s;
    }
    __syncthreads();
    if (tid == 0) {
        int p = 0;
        for (int k = 0; k < ns; ++k) { int len = segP[k]; segP[k] = p; p += len; }
        segP[ns] = p;
        shTot[0] = p;
    }
    __syncthreads();

    const float step = 0.015625f;
    const float h2 = 0.03125f * 0.03125f;
    const float cc = poly6_c();
    int total = shTot[0];

    int l = tid & 63, w = tid >> 6;
    int cx = X0 + 4 * (w >> 1) + (l >> 4);
    int cy = Y0 + 4 * (w & 1) + ((l >> 2) & 3);
    int cz0 = Z0 + (l & 3);
    float xc  = ((float)cx  + 0.5f) * step;
    float yc  = ((float)cy  + 0.5f) * step;
    float zc0 = ((float)cz0 + 0.5f) * step;
    float zc1 = zc0 + 4.0f * step;

    float a00 = 0.f, a01 = 0.f, a02 = 0.f, a03 = 0.f;
    float a10 = 0.f, a11 = 0.f, a12 = 0.f, a13 = 0.f;

    int nchunks = (total + 255) >> 8;
    for (int ch = 0; ch < nchunks; ++ch) {
        __syncthreads();
        int jj = (ch << 8) + tid;
        if (jj < total) {
            int k = 0;
            while (jj >= segP[k + 1]) ++k;
            int idx = segS[k] + (jj - segP[k]);
            *(float4*)(plist + tid * 8)     = *(const float4*)(payload + idx * 8);
            *(float4*)(plist + tid * 8 + 4) = *(const float4*)(payload + idx * 8 + 4);
        }
        __syncthreads();
        int cnt = imin(256, total - (ch << 8));
        for (int p = 0; p < cnt; ++p) {
            float4 pa = *(const float4*)(plist + p * 8);     // broadcast read
            float dx = pa.x - xc, dy = pa.y - yc;
            float dxy2 = fmaf(dy, dy, dx * dx);
            if (!__any(dxy2 <= h2)) continue;                // wave-coherent skip
            float4 pv = *(const float4*)(plist + p * 8 + 4);
            float dz0 = pa.z - zc0;
            float d20 = fmaf(dz0, dz0, dxy2);
            float u0 = fmaxf(h2 - d20, 0.f);
            float w0 = (cc * u0) * (u0 * u0);
            a00 = fmaf(w0, pa.w, a00);
            a01 = fmaf(w0, pv.x, a01);
            a02 = fmaf(w0, pv.y, a02);
            a03 = fmaf(w0, pv.z, a03);
            float dz1 = pa.z - zc1;
            float d21 = fmaf(dz1, dz1, dxy2);
            float u1 = fmaxf(h2 - d21, 0.f);
            float w1 = (cc * u1) * (u1 * u1);
            a10 = fmaf(w1, pa.w, a10);
            a11 = fmaf(w1, pv.x, a11);
            a12 = fmaf(w1, pv.y, a12);
            a13 = fmaf(w1, pv.z, a13);
        }
    }

    size_t cellBase = (size_t)(((b * 64 + cx) * 64 + cy) * 64);
    short8 o;
    o[0] = (short)bf16_rne(a00); o[1] = (short)bf16_rne(a01);
    o[2] = (short)bf16_rne(a02); o[3] = (short)bf16_rne(a03);
    o[4] = 0; o[5] = 0; o[6] = 0; o[7] = 0;
    *(short8*)(g8 + (cellBase + cz0) * 8) = o;
    o[0] = (short)bf16_rne(a10); o[1] = (short)bf16_rne(a11);
    o[2] = (short)bf16_rne(a12); o[3] = (short)bf16_rne(a13);
    *(short8*)(g8 + (cellBase + cz0 + 4) * 8) = o;
}

// ---------------- MFMA implicit-GEMM 3x3x3 conv (B in LDS, h-major) --------
// 2x4-column tile; wave owns one x-col + y-pair (2 accs) per z-tile; both
// z-tiles' accumulators live across halves (h-major phases: h0t0 h0t1 h1t0
// h1t1).  B-half (27 kt x 1 KB = 27.6 KB) is loaded to LDS ONCE per block
// per half -- kills the per-wave global B re-read (was ~221 MB L2 traffic
// per dispatch, the dominant non-MFMA term) and removes all global ops +
// vmcnt waits from the MFMA inner loop.  A is double-buffered (2 x 26.1 KB);
// total LDS 79.9 KB -> 2 blocks/CU, grid 1024 = balanced 512+512 (no tail).
// setprio removed (hurts lockstep GEMM structures, m190).
template <int ICG, int KT, bool FINAL>
__global__ __launch_bounds__(256, 2) void mfma_conv_kernel(
    const ushortT* __restrict__ in, const short* __restrict__ Bpack,
    const float* __restrict__ bias, const float* __restrict__ alpha,
    const float* __restrict__ zguard, void* __restrict__ outv) {
    constexpr int CIN  = ICG * 8;
    constexpr int NCHP = (ICG == 1) ? (24 * 34) : (24 * 2 * 34);  // 16B chunks
    constexpr int ABUF = NCHP * 8;               // shorts per A buffer
    constexpr int BKT  = (ICG == 1) ? KT : 27;   // kt per resident B
    constexpr int BBUF = BKT * 512;              // shorts
    __shared__ short lds[2 * ABUF + BBUF];

    // XCD swizzle: contiguous slab per XCD (1024 blocks -> 128 per XCD)
    int wg = ((blockIdx.x & 7) << 7) | (blockIdx.x >> 3);
    int yq = wg & 15, xp = (wg >> 4) & 31, b = wg >> 9;
    int X0 = xp * 2, Y0 = yq * 4;
    int tid = threadIdx.x;
    const ushortT* inb = in + (size_t)b * (64 * 64 * 64 * CIN);

    int l = tid & 63, w = tid >> 6;
    int wx = w >> 1, wy2 = (w & 1) * 2;           // owned x-col, y-pair base
    int n = l & 31, q = l >> 5;
    int laneZ = (l & 31) * 8;                     // z-row offset (shorts)
    float bval = FINAL ? (n < 4 ? bias[n] : 0.f) : bias[n];
    const short* Bl = lds + 2 * ABUF;

    // issue A staging for phase p (no wait); ICG4: p = h*2 + t (h-major)
    auto stageA = [&](int p) {
        int h, t;
        if constexpr (ICG == 1) { h = 0; t = p; } else { h = p >> 1; t = p & 1; }
        int zb = t * 32;
        short* dst = lds + (p & 1) * ABUF;
#pragma unroll
        for (int it = 0; it < (NCHP + 255) / 256; ++it) {
            int ccid = it * 256 + tid;
            if (ccid < NCHP) {
                int col, icg2, zi;
                if constexpr (ICG == 1) {
                    col = ccid / 34; zi = ccid - col * 34; icg2 = 0;
                } else {
                    col = ccid / 68;
                    int rem = ccid - col * 68;
                    icg2 = rem / 34; zi = rem - icg2 * 34;
                }
                int gx = X0 + col / 6 - 1;
                int gy = Y0 + col % 6 - 1;
                int gz = zb + zi - 1;
                const void* src = (const void*)zguard;
                if ((unsigned)gx < 64u && (unsigned)gy < 64u && (unsigned)gz < 64u)
                    src = (const void*)(inb +
                        ((size_t)(((gx * 64) + gy) * 64 + gz)) * CIN + (h * 2 + icg2) * 8);
                load_lds16(src, (void*)(dst + ccid * 8));
            }
        }
    };

    // issue B-half staging into the LDS B region (no wait)
    auto loadB = [&](int h) {
        const short* src0 = Bpack + (size_t)h * BBUF;
        short* dst = lds + 2 * ABUF;
        constexpr int NB = BBUF / 8;              // 16B chunks
#pragma unroll
        for (int it = 0; it < (NB + 255) / 256; ++it) {
            int ccid = it * 256 + tid;
            if (ccid < NB)
                load_lds16((const void*)(src0 + ccid * 8), (void*)(dst + ccid * 8));
        }
    };

    // compute one phase from A buffer (p&1) + resident B, into acc pair
    auto computeP = [&](int p, float16& c0, float16& c1) {
        const short* lb = lds + (p & 1) * ABUF;
        if constexpr (ICG == 1) {
#pragma unroll
            for (int kt = 0; kt < KT; ++kt) {
                short8 bcur = *(const short8*)(Bl + kt * 512 + l * 8);
                int tap0 = kt * 2, tap1 = kt * 2 + 1;
                if (tap1 > 26) tap1 = 26;         // B is zero there
                int dx0 = tap0 / 9, r0 = tap0 - dx0 * 9, dy0 = r0 / 3, dz0 = r0 - dy0 * 3;
                int dx1 = tap1 / 9, r1 = tap1 - dx1 * 9, dy1 = r1 / 3, dz1 = r1 - dy1 * 3;
#define AOFS1(c) (q ? ((((wx + dx1) * 6 + ((c) + dy1)) * 34 + dz1) * 8) \
                    : ((((wx + dx0) * 6 + ((c) + dy0)) * 34 + dz0) * 8))
                short8 a0 = *(const short8*)(lb + AOFS1(wy2) + laneZ);
                short8 a1 = *(const short8*)(lb + AOFS1(wy2 + 1) + laneZ);
#undef AOFS1
                c0 = __builtin_amdgcn_mfma_f32_32x32x16_bf16(a0, bcur, c0, 0, 0, 0);
                c1 = __builtin_amdgcn_mfma_f32_32x32x16_bf16(a1, bcur, c1, 0, 0, 0);
            }
        } else {
#pragma unroll
            for (int g = 0; g < 9; ++g) {
                int dx = g / 3, dz = g - dx * 3;
                short8 fr[4];
#pragma unroll
                for (int k = 0; k < 4; ++k) {
                    int ofs = ((((wx + dx) * 6 + (wy2 + k)) * 2 + q) * 34 + dz) * 8;
                    fr[k] = *(const short8*)(lb + ofs + laneZ);
                }
#pragma unroll
                for (int dy = 0; dy < 3; ++dy) {
                    short8 bcur = *(const short8*)(Bl + (g * 3 + dy) * 512 + l * 8);
                    c0 = __builtin_amdgcn_mfma_f32_32x32x16_bf16(fr[0 + dy], bcur, c0, 0, 0, 0);
                    c1 = __builtin_amdgcn_mfma_f32_32x32x16_bf16(fr[1 + dy], bcur, c1, 0, 0, 0);
                }
            }
        }
    };

    auto epi = [&](int t, const float16& c0, const float16& c1) {
        int Z0 = t * 32;
        size_t base0 = (size_t)(((b * 64 + X0 + wx) * 64 + (Y0 + wy2)) * 64) + Z0;
        if constexpr (FINAL) {
            float* out = (float*)outv;
            if (n < 4) {
#pragma unroll
                for (int r = 0; r < 16; ++r) {
                    int z = (r & 3) + 8 * (r >> 2) + 4 * q;
                    out[(base0 + z) * 4 + n]      = c0[r];
                    out[(base0 + 64 + z) * 4 + n] = c1[r];
                }
            }
        } else {
            float a = alpha[0];
            ushortT* out = (ushortT*)outv;
#pragma unroll
            for (int r = 0; r < 16; ++r) {
                int z = (r & 3) + 8 * (r >> 2) + 4 * q;
                float v0 = c0[r]; v0 = v0 >= 0.f ? v0 : a * v0;
                out[(base0 + z) * 32 + n] = bf16_rne(v0);
                float v1 = c1[r]; v1 = v1 >= 0.f ? v1 : a * v1;
                out[(base0 + 64 + z) * 32 + n] = bf16_rne(v1);
            }
        }
    };

    float16 a00, a01, a10, a11;                   // tile0/tile1 acc pairs
#pragma unroll
    for (int r = 0; r < 16; ++r) {
        a00[r] = bval; a01[r] = bval; a10[r] = bval; a11[r] = bval;
    }

    stageA(0);
    loadB(0);

    if constexpr (ICG == 1) {
        __syncthreads();                          // A(0)+B arrived
        stageA(1);
        computeP(0, a00, a01);
        epi(0, a00, a01);
        __syncthreads();                          // A(1) arrived
        computeP(1, a10, a11);
        epi(1, a10, a11);
    } else {
        __syncthreads();                          // A(0)+B(0) arrived
        stageA(1);
        computeP(0, a00, a01);                    // h0 t0
        __syncthreads();                          // A(1) arrived
        stageA(2);
        computeP(1, a10, a11);                    // h0 t1
        __syncthreads();                          // all waves done with B(0); A(2) drained
        loadB(1);
        __syncthreads();                          // B(1) arrived
        stageA(3);
        computeP(2, a00, a01);                    // h1 t0
        epi(0, a00, a01);
        __syncthreads();                          // A(3) arrived
        computeP(3, a10, a11);                    // h1 t1
        epi(1, a10, a11);
    }
}

// ---------------- grid2particles (trilinear gather, fp32 grid) ----------------
__global__ __launch_bounds__(256) void gather_kernel(
    const float* __restrict__ grid, const float* __restrict__ locs,
    float* __restrict__ out) {
    int t = blockIdx.x * blockDim.x + threadIdx.x;
    if (t >= BATCH * NPART) return;
    int b = t >> 15;

    float px = locs[t * 3 + 0] * 64.0f - 0.5f;
    float py = locs[t * 3 + 1] * 64.0f - 0.5f;
    float pz = locs[t * 3 + 2] * 64.0f - 0.5f;
    int ix = (int)floorf(px);
    int iy = (int)floorf(py);
    int iz = (int)floorf(pz);
    float fx = px - (float)ix;
    float fy = py - (float)iy;
    float fz = pz - (float)iz;

    const float* gb = grid + (size_t)b * GD * GD * GD * 4;
    float o0 = 0.f, o1 = 0.f, o2 = 0.f, o3 = 0.f;

#pragma unroll
    for (int dx = 0; dx < 2; ++dx) {
        int x = ix + dx;
        if ((unsigned)x > 63u) continue;
        float wx = dx ? fx : 1.0f - fx;
#pragma unroll
        for (int dy = 0; dy < 2; ++dy) {
            int y = iy + dy;
            if ((unsigned)y > 63u) continue;
            float wy = dy ? fy : 1.0f - fy;
#pragma unroll
            for (int dz = 0; dz < 2; ++dz) {
                int z = iz + dz;
                if ((unsigned)z > 63u) continue;
                float wz = dz ? fz : 1.0f - fz;
                float w = wx * wy * wz;
                const float4 g = *(const float4*)(gb + (size_t)(((x * GD) + y) * GD + z) * 4);
                o0 += w * g.x; o1 += w * g.y; o2 += w * g.z; o3 += w * g.w;
            }
        }
    }
    out[t * 4 + 0] = o0;
    out[t * 4 + 1] = o1;
    out[t * 4 + 2] = o2;
    out[t * 4 + 3] = o3;
}

extern "C" void kernel_launch(void* const* d_in, const int* in_sizes, int n_in,
                              void* d_out, int out_size, void* d_ws, size_t ws_size,
                              hipStream_t stream) {
    const float* locs    = (const float*)d_in[0];
    const float* data    = (const float*)d_in[1];
    const float* density = (const float*)d_in[2];
    const float* W0 = (const float*)d_in[3];
    const float* b0 = (const float*)d_in[4];
    const float* W1 = (const float*)d_in[5];
    const float* b1 = (const float*)d_in[6];
    const float* W2 = (const float*)d_in[7];
    const float* b2 = (const float*)d_in[8];
    const float* W3 = (const float*)d_in[9];
    const float* b3 = (const float*)d_in[10];
    const float* a0 = (const float*)d_in[11];
    const float* a1 = (const float*)d_in[12];
    const float* a2 = (const float*)d_in[13];
    float* out = (float*)d_out;

    char* ws = (char*)d_ws;
    ushortT* g8  = (ushortT*)(ws);                       // 8 MB bf16 8ch
    ushortT* gA  = (ushortT*)(ws + 8388608);             // 33.5 MB bf16 32ch
    ushortT* gB  = (ushortT*)(ws + 41943040);            // 33.5 MB bf16 32ch
    float*  gF   = (float*)(ws + 75497472);              // 8 MB fp32 4ch
    short*  Bp   = (short*)(ws + 83886080);              // 176*512*2 = 180224 B
    short*  Bp0  = Bp;                                   // kt 0..13
    short*  Bp1  = Bp + 14 * 512;                        // kt 14..67
    short*  Bp2  = Bp + 68 * 512;                        // kt 68..121
    short*  Bp3  = Bp + 122 * 512;                       // kt 122..175
    float* zguard   = (float*)(ws + 84066240);           // 64 B zeros (16 ints)
    int*   counts   = (int*)(ws + 84066304);             // 65536 ints
    int*   cursor   = (int*)(ws + 84328448);             // 65536 ints
    int*   offsets  = (int*)(ws + 84590592);             // 65537 ints
    int*   blockSum = (int*)(ws + 84852752);             // 256 ints
    float* payload  = (float*)(ws + 84853888);           // 65536*8 floats = 2 MB

    // ---- fused prep: zero (zguard+counts+cursor) + weight repack ----
    prep_kernel<<<513 + 352, 256, 0, stream>>>((int*)zguard, W0, W1, W2, W3, Bp);

    bin_count_kernel<<<(BATCH * NPART) / 256, 256, 0, stream>>>(locs, counts);
    scanA_kernel<<<256, 256, 0, stream>>>(counts, offsets, blockSum);
    scanB_kernel<<<256, 256, 0, stream>>>(offsets, blockSum);
    bin_scatter_kernel<<<(BATCH * NPART) / 256, 256, 0, stream>>>(
        locs, data, density, offsets, cursor, payload);

    // ---- particles -> bf16 grid (cell-owner gather, no atomics) ----
    splat_gather_kernel<<<BATCH * 512, 256, 0, stream>>>(payload, offsets, g8);

    // ---- conv chain (B-in-LDS, A dbuf, 2x4 tile, 2 blocks/CU) ----
    const int CGRID = 1024;   // 2 b x 32 xp x 16 yq (each block does z 0-31, 32-63)
    mfma_conv_kernel< 1, 14, false><<<CGRID, 256, 0, stream>>>(g8, Bp0, b0, a0, zguard, gA);
    mfma_conv_kernel< 4, 54, false><<<CGRID, 256, 0, stream>>>(gA, Bp1, b1, a1, zguard, gB);
    mfma_conv_kernel< 4, 54, false><<<CGRID, 256, 0, stream>>>(gB, Bp2, b2, a2, zguard, gA);
    mfma_conv_kernel< 4, 54, true ><<<CGRID, 256, 0, stream>>>(gA, Bp3, b3, b3, zguard, gF);

    // ---- grid -> particles ----
    gather_kernel<<<(BATCH * NPART) / 256, 256, 0, stream>>>(gF, locs, out);
}